// Round 11
// baseline (198.922 us; speedup 1.0000x reference)
//
#include <hip/hip_runtime.h>

// Problem constants
#define B_    4096
#define T_    32
#define OUT_  8
#define BTILE 32

typedef _Float16 f16;
typedef _Float16 f16x2 __attribute__((ext_vector_type(2)));
typedef _Float16 f16x4 __attribute__((ext_vector_type(4)));
typedef _Float16 f16x8 __attribute__((ext_vector_type(8)));
typedef float    f32x4 __attribute__((ext_vector_type(4)));

#define MFMA16(a, b, c) __builtin_amdgcn_mfma_f32_16x16x32_f16((a), (b), (c), 0, 0, 0)

// ---- workspace layout (bytes). Total ~25 MB ----
#define WS_AENC 16384u                    // [B*T][16] f16 = 4 MB
#define WS_OENC (WS_AENC + 4194304u)      // 4 MB
#define WS_H    (WS_OENC + 4194304u)      // f16 relaid H: 16 MB
#define WS_U    (WS_H + 16842752u)        // u exchange: 128 bt x 32 b x 32 m f32 = 512 KB
#define WS_FLAG (WS_U + 524288u)          // 128 ints (u-ready flags)
#define WS_CNT  (WS_FLAG + 512u)          // 8 xid x 16 tau ints (lockstep counters)
// H granule (1 KB) per (t, p, sl, nf): byte ((t*32+p)*16 + sl*2 + nf)*1024 + lane*16
// slot h*4+r = Ht[p][j=2sl+h][kk=g4*4+r][l=nf*16+m16] * (1/8)

// LDS W/M layout (f16 elements), bank-conflict-padded:
//   idx(b, k, n) = b*1064 + ((k>>2)&3)*264 + n*8 + (k>>4)*4 + (k&3)
#define BSTR 1064
#define KGRP 264
#define WSZ  (32 * BSTR)   // 34048 f16 = 68096 B

// ------------------- prep 1: fuse encoder weights -------------------
__global__ void k_fuse_w(const float* __restrict__ Wa0, const float* __restrict__ ba0,
                         const float* __restrict__ Wa1, const float* __restrict__ ba1,
                         const float* __restrict__ Wo0, const float* __restrict__ bo0,
                         const float* __restrict__ Wo1, const float* __restrict__ bo1,
                         float* __restrict__ ws) {
  const int tid = threadIdx.x;  // 256 threads, 1 block
  for (int idx = tid; idx < 1024; idx += 256) {
    const int d = idx >> 4, j = idx & 15;
    float s = 0.f, s2 = 0.f;
    for (int h = 0; h < 128; ++h) {
      s  += Wa0[d * 128 + h] * Wa1[h * 16 + j];
      s2 += Wo0[d * 128 + h] * Wo1[h * 16 + j];
    }
    ws[idx] = s;
    ws[1024 + idx] = s2;
  }
  if (tid < 16) {
    float s = 0.f, s2 = 0.f;
    for (int h = 0; h < 128; ++h) {
      s  += ba0[h] * Wa1[h * 16 + tid];
      s2 += bo0[h] * Wo1[h * 16 + tid];
    }
    ws[2048 + tid] = s + ba1[tid];
    ws[2112 + tid] = s2 + bo1[tid];
  }
}

// ------------------- prep 2: MFMA encoder (f16 in, f32 acc) -------------------
__global__ void k_encode(const float* __restrict__ action, const float* __restrict__ obs,
                         const float* __restrict__ ws,
                         f16* __restrict__ aenc, f16* __restrict__ oenc) {
  const int tid = threadIdx.x;
  const int lane = tid & 63;
  const int v = tid >> 6;
  const int m16 = lane & 15, g4 = lane >> 4;
  const int bt0 = blockIdx.x * 64 + v * 16;

  f16x8 wbA[2], wbB[2];
  #pragma unroll
  for (int ks = 0; ks < 2; ++ks)
    #pragma unroll
    for (int h = 0; h < 2; ++h)
      #pragma unroll
      for (int r = 0; r < 4; ++r) {
        const int d = ks * 32 + h * 16 + g4 * 4 + r;
        wbA[ks][h * 4 + r] = (f16)ws[d * 16 + m16];
        wbB[ks][h * 4 + r] = (f16)ws[1024 + d * 16 + m16];
      }
  const float biasA = ws[2048 + m16], biasB = ws[2112 + m16];
  f32x4 accA = {biasA, biasA, biasA, biasA};
  f32x4 accB = {biasB, biasB, biasB, biasB};

  const float* ar = action + (size_t)(bt0 + m16) * 64;
  const float* br = obs    + (size_t)(bt0 + m16) * 64;
  #pragma unroll
  for (int ks = 0; ks < 2; ++ks) {
    f16x8 aa, oo;
    #pragma unroll
    for (int h = 0; h < 2; ++h) {
      const f32x4 a4 = *(const f32x4*)(ar + ks * 32 + h * 16 + g4 * 4);
      const f32x4 o4 = *(const f32x4*)(br + ks * 32 + h * 16 + g4 * 4);
      #pragma unroll
      for (int r = 0; r < 4; ++r) { aa[h * 4 + r] = (f16)a4[r]; oo[h * 4 + r] = (f16)o4[r]; }
    }
    accA = MFMA16(aa, wbA[ks], accA);
    accB = MFMA16(oo, wbB[ks], accB);
  }
  #pragma unroll
  for (int r = 0; r < 4; ++r) {
    aenc[(size_t)(bt0 + g4 * 4 + r) * 16 + m16] = (f16)accA[r];
    oenc[(size_t)(bt0 + g4 * 4 + r) * 16 + m16] = (f16)accB[r];
  }
}

// ------------------- prep 3: relayout H -> f16 granules, scaled by 1/8 -------------------
__global__ void k_hprep(const float* __restrict__ Hf, const float* __restrict__ Hm,
                        const float* __restrict__ Hl, f16* __restrict__ hdst) {
  const int x = blockIdx.x * 256 + threadIdx.x;     // < 1048576
  const int lane = x & 63;
  const int gid = x >> 6;
  const int nf = gid & 1, s = (gid >> 1) & 7, p = (gid >> 4) & 31, t = gid >> 9;
  const int m16 = lane & 15, g4 = lane >> 4;
  const int l = nf * 16 + m16;
  f16x8 gout;
  #pragma unroll
  for (int h = 0; h < 2; ++h) {
    const int j = 2 * s + h;
    #pragma unroll
    for (int r = 0; r < 4; ++r) {
      const int kk = g4 * 4 + r;
      float vsrc;
      if (t == 0)       vsrc = (p == 0) ? Hf[(j * 16 + kk) * 32 + l] : 0.f;
      else if (t == 31) vsrc = (l < 8) ? Hl[((p * 16 + j) * 16 + kk) * 8 + l] : 0.f;
      else              vsrc = Hm[((((size_t)(t - 1) * 32 + p) * 16 + j) * 16 + kk) * 32 + l];
      gout[h * 4 + r] = (f16)(vsrc * 0.125f);
    }
  }
  *(f16x8*)((char*)hdst + (size_t)x * 16) = gout;
}

// ------------------- main fused kernel: associative 2-way T-split -------------------
// 256 blocks x 512 threads (1 block/CU). Block (bt, g): b-rows [32bt, +32), t in [16g, +16).
// g = blockIdx&1 and XCD = blockIdx%8 => each XCD hosts 32 same-g blocks reading the SAME
// 512 KB slab per tau. A bounded per-XCD lockstep sync keeps them L2-resident (timing-only:
// timeout cannot affect results). Per tau: [M-form + packed M-store] bar [W-update] bar.
__launch_bounds__(512)
__global__ void k_main(const f16* __restrict__ aenc, const f16* __restrict__ oenc,
                       const char* __restrict__ hws, float* __restrict__ uex,
                       int* __restrict__ flag, int* __restrict__ cnt,
                       float* __restrict__ out) {
  __shared__ __align__(16) f16 Wl[WSZ];     // 66.5 KB
  __shared__ __align__(16) f16 Ml[WSZ];     // 66.5 KB
  __shared__ float u_lds[1024];             // 4 KB

  const int tid  = threadIdx.x;
  const int lane = tid & 63;
  const int w    = tid >> 6;       // 0..7 ; wave owns p in [4w, 4w+4)
  const int m16  = lane & 15;
  const int g4   = lane >> 4;
  const int bt   = blockIdx.x >> 1;
  const int g    = blockIdx.x & 1;
  const int xid  = blockIdx.x & 7;
  const int b0   = bt * BTILE;
  const int t0   = g * 16;

  // ---- enc regs for t = t0 ----
  const f16* ap0 = aenc + ((size_t)(b0 + m16) * T_ + t0) * 16;
  const f16* ap1 = aenc + ((size_t)(b0 + 16 + m16) * T_ + t0) * 16;
  f16x8 aL0 = *(const f16x8*)ap0, aH0 = *(const f16x8*)(ap0 + 8);
  f16x8 aL1 = *(const f16x8*)ap1, aH1 = *(const f16x8*)(ap1 + 8);
  f16x4 ovA = *(const f16x4*)(oenc + ((size_t)(b0 + m16) * T_ + t0) * 16 + g4 * 4);
  f16x4 ovB = *(const f16x4*)(oenc + ((size_t)(b0 + 16 + m16) * T_ + t0) * 16 + g4 * 4);

  const char* hl = hws + (size_t)lane * 16;
  const f32x4 zz = {0.f, 0.f, 0.f, 0.f};

  f16x8 bufA[8], bufB[8];
  {
    const char* ga = hl + (size_t)((t0 * 32 + 4 * w) * 16) * 1024;
    #pragma unroll
    for (int i = 0; i < 8; ++i) bufA[i] = *(const f16x8*)(ga + i * 1024);
  }

  #pragma clang loop unroll(disable)
  for (int tau = 0; tau < 16; ++tau) {
    const int t = t0 + tau;

    // ---- bounded per-XCD lockstep sync (perf-only; safe on timeout) ----
    if (tid == 0) {
      int* c = cnt + (xid * 16 + tau);
      __hip_atomic_fetch_add(c, 1, __ATOMIC_RELAXED, __HIP_MEMORY_SCOPE_AGENT);
      int it = 0;
      while (it < 512 &&
             __hip_atomic_load(c, __ATOMIC_RELAXED, __HIP_MEMORY_SCOPE_AGENT) < 32) {
        __builtin_amdgcn_s_sleep(4);
        ++it;
      }
    }
    __builtin_amdgcn_s_barrier();

    // ---- build E fragments (reused across all p) ----
    f16x8 efr0[8], efr1[8];
    #pragma unroll
    for (int sl = 0; sl < 8; ++sl) {
      const f16 a00 = (sl < 4) ? aL0[2 * sl]     : aH0[2 * sl - 8];
      const f16 a01 = (sl < 4) ? aL0[2 * sl + 1] : aH0[2 * sl - 7];
      const f16 a10 = (sl < 4) ? aL1[2 * sl]     : aH1[2 * sl - 8];
      const f16 a11 = (sl < 4) ? aL1[2 * sl + 1] : aH1[2 * sl - 7];
      #pragma unroll
      for (int r = 0; r < 4; ++r) {
        efr0[sl][r] = a00 * ovA[r]; efr0[sl][4 + r] = a01 * ovA[r];
        efr1[sl][r] = a10 * ovB[r]; efr1[sl][4 + r] = a11 * ovB[r];
      }
    }
    // prefetch next-tau enc (enc regs dead after E build)
    const int tn = (tau < 15) ? t + 1 : t;
    {
      const f16* an0 = aenc + ((size_t)(b0 + m16) * T_ + tn) * 16;
      const f16* an1 = aenc + ((size_t)(b0 + 16 + m16) * T_ + tn) * 16;
      aL0 = *(const f16x8*)an0; aH0 = *(const f16x8*)(an0 + 8);
      aL1 = *(const f16x8*)an1; aH1 = *(const f16x8*)(an1 + 8);
      ovA = *(const f16x4*)(oenc + ((size_t)(b0 + m16) * T_ + tn) * 16 + g4 * 4);
      ovB = *(const f16x4*)(oenc + ((size_t)(b0 + 16 + m16) * T_ + tn) * 16 + g4 * 4);
    }

    // ---- form M rows p = 4w..4w+3; accumulate all 4 pp for packed stores ----
    f32x4 acc[4][2][2];
    #pragma unroll
    for (int pp = 0; pp < 4; ++pp) {
      const int p = 4 * w + pp;
      acc[pp][0][0] = zz; acc[pp][0][1] = zz; acc[pp][1][0] = zz; acc[pp][1][1] = zz;
      {
        const char* gb = hl + ((size_t)((t * 32 + p) * 16) + 8) * 1024;
        #pragma unroll
        for (int i = 0; i < 8; ++i) bufB[i] = *(const f16x8*)(gb + i * 1024);
      }
      __builtin_amdgcn_s_setprio(1);
      #pragma unroll
      for (int sl = 0; sl < 4; ++sl) {
        acc[pp][0][0] = MFMA16(efr0[sl], bufA[sl * 2 + 0], acc[pp][0][0]);
        acc[pp][1][0] = MFMA16(efr1[sl], bufA[sl * 2 + 0], acc[pp][1][0]);
        acc[pp][0][1] = MFMA16(efr0[sl], bufA[sl * 2 + 1], acc[pp][0][1]);
        acc[pp][1][1] = MFMA16(efr1[sl], bufA[sl * 2 + 1], acc[pp][1][1]);
      }
      __builtin_amdgcn_s_setprio(0);
      {
        const int pnext = (pp < 3) ? p + 1 : 4 * w;
        const int tnext = (pp < 3) ? t : tn;
        const char* ga = hl + (size_t)((tnext * 32 + pnext) * 16) * 1024;
        #pragma unroll
        for (int i = 0; i < 8; ++i) bufA[i] = *(const f16x8*)(ga + i * 1024);
      }
      __builtin_amdgcn_s_setprio(1);
      #pragma unroll
      for (int sl = 4; sl < 8; ++sl) {
        acc[pp][0][0] = MFMA16(efr0[sl], bufB[(sl - 4) * 2 + 0], acc[pp][0][0]);
        acc[pp][1][0] = MFMA16(efr1[sl], bufB[(sl - 4) * 2 + 0], acc[pp][1][0]);
        acc[pp][0][1] = MFMA16(efr0[sl], bufB[(sl - 4) * 2 + 1], acc[pp][0][1]);
        acc[pp][1][1] = MFMA16(efr1[sl], bufB[(sl - 4) * 2 + 1], acc[pp][1][1]);
      }
      __builtin_amdgcn_s_setprio(0);
    }

    // ---- packed M-store: k = 4w+pp -> (k&3)=pp contiguous => f16x4 (b64) writes ----
    #pragma unroll
    for (int mf = 0; mf < 2; ++mf)
      #pragma unroll
      for (int nf = 0; nf < 2; ++nf)
        #pragma unroll
        for (int r = 0; r < 4; ++r) {
          const int b = mf * 16 + g4 * 4 + r;
          const int n = nf * 16 + m16;
          f16x4 v;
          v[0] = (f16)acc[0][mf][nf][r];
          v[1] = (f16)acc[1][mf][nf][r];
          v[2] = (f16)acc[2][mf][nf][r];
          v[3] = (f16)acc[3][mf][nf][r];
          *(f16x4*)&Ml[b * BSTR + (w & 3) * KGRP + n * 8 + (w >> 2) * 4] = v;
        }
    asm volatile("s_waitcnt lgkmcnt(0)" ::: "memory");
    __builtin_amdgcn_s_barrier();

    if (tau == 0) {
      // W := M (transposed copy: k <-> n)
      #pragma unroll
      for (int rep = 0; rep < 64; ++rep) {
        const int e = tid + rep * 512;
        const int b = e >> 10, k = (e >> 5) & 31, rho = e & 31;
        Wl[b * BSTR + ((k >> 2) & 3) * KGRP + rho * 8 + (k >> 4) * 4 + (k & 3)] =
          Ml[b * BSTR + ((rho >> 2) & 3) * KGRP + k * 8 + (rho >> 4) * 4 + (rho & 3)];
      }
      asm volatile("s_waitcnt lgkmcnt(0)" ::: "memory");
      __builtin_amdgcn_s_barrier();
    } else {
      // W <- W*M : wave w handles b in [4w, 4w+4)
      f32x4 n00[4], n01[4], n10[4], n11[4];
      #pragma unroll
      for (int bb = 0; bb < 4; ++bb) {
        const int bx = (4 * w + bb) * BSTR + g4 * KGRP;
        const f16x8 A0 = *(const f16x8*)&Wl[bx + m16 * 8];
        const f16x8 A1 = *(const f16x8*)&Wl[bx + (16 + m16) * 8];
        const f16x8 B0 = *(const f16x8*)&Ml[bx + m16 * 8];
        const f16x8 B1 = *(const f16x8*)&Ml[bx + (16 + m16) * 8];
        n00[bb] = MFMA16(A0, B0, zz);
        n01[bb] = MFMA16(A0, B1, zz);
        n10[bb] = MFMA16(A1, B0, zz);
        n11[bb] = MFMA16(A1, B1, zz);
      }
      __builtin_amdgcn_s_barrier();   // all W reads complete before overwrite
      #pragma unroll
      for (int bb = 0; bb < 4; ++bb) {
        const int bx = (4 * w + bb) * BSTR + (m16 >> 2) * KGRP + (m16 & 3);
        #pragma unroll
        for (int rr = 0; rr < 4; ++rr) {
          const int pA = (g4 * 4 + rr) * 8, pB = (16 + g4 * 4 + rr) * 8;
          Wl[bx + pA]     = (f16)n00[bb][rr];   // k = m16,    n = g4*4+rr
          Wl[bx + pA + 4] = (f16)n01[bb][rr];   // k = 16+m16
          Wl[bx + pB]     = (f16)n10[bb][rr];   // k = m16,    n = 16+g4*4+rr
          Wl[bx + pB + 4] = (f16)n11[bb][rr];   // k = 16+m16
        }
      }
      // W-store drained by the lgkmcnt(0) before the NEXT tau's barrier (or epilogue)
    }
  }

  asm volatile("s_waitcnt lgkmcnt(0)" ::: "memory");
  __builtin_amdgcn_s_barrier();

  // ---- epilogue: exchange u = W0[0,:] and fold ----
  if (g == 0) {
    #pragma unroll
    for (int rep = 0; rep < 2; ++rep) {
      const int e = tid + rep * 512;          // e = bb*32 + m
      const int bb = e >> 5, m = e & 31;
      const float v = (float)Wl[bb * BSTR + ((m >> 2) & 3) * KGRP + (m >> 4) * 4 + (m & 3)];
      __hip_atomic_store(uex + bt * 1024 + e, v, __ATOMIC_RELAXED, __HIP_MEMORY_SCOPE_AGENT);
    }
    __syncthreads();
    if (tid == 0)
      __hip_atomic_store(flag + bt, 1, __ATOMIC_RELEASE, __HIP_MEMORY_SCOPE_AGENT);
  } else {
    if (tid == 0) {
      while (__hip_atomic_load(flag + bt, __ATOMIC_ACQUIRE, __HIP_MEMORY_SCOPE_AGENT) == 0)
        __builtin_amdgcn_s_sleep(16);
    }
    __syncthreads();
    #pragma unroll
    for (int rep = 0; rep < 2; ++rep) {
      const int e = tid + rep * 512;
      u_lds[e] = __hip_atomic_load(uex + bt * 1024 + e, __ATOMIC_RELAXED, __HIP_MEMORY_SCOPE_AGENT);
    }
    __syncthreads();
    if (tid < 256) {
      const int bb = tid >> 3, o = tid & 7;
      float s = 0.f;
      #pragma unroll
      for (int rho = 0; rho < 32; ++rho)
        s += u_lds[bb * 32 + rho] *
             (float)Wl[bb * BSTR + (o >> 2) * KGRP + rho * 8 + (o & 3)];
      out[(size_t)(b0 + bb) * OUT_ + o] = s * 0x1p96f;   // undo (1/8)^32 scaling
    }
  }
}

extern "C" void kernel_launch(void* const* d_in, const int* in_sizes, int n_in,
                              void* d_out, int out_size, void* d_ws, size_t ws_size,
                              hipStream_t stream) {
  (void)in_sizes; (void)n_in; (void)out_size; (void)ws_size;
  const float* action = (const float*)d_in[0];
  const float* obs    = (const float*)d_in[1];
  const float* Wa0 = (const float*)d_in[2];
  const float* ba0 = (const float*)d_in[3];
  const float* Wa1 = (const float*)d_in[4];
  const float* ba1 = (const float*)d_in[5];
  const float* Wo0 = (const float*)d_in[6];
  const float* bo0 = (const float*)d_in[7];
  const float* Wo1 = (const float*)d_in[8];
  const float* bo1 = (const float*)d_in[9];
  const float* Hf  = (const float*)d_in[10];
  const float* Hm  = (const float*)d_in[11];
  const float* Hl  = (const float*)d_in[12];
  char*  ws  = (char*)d_ws;
  float* out = (float*)d_out;

  k_fuse_w<<<1, 256, 0, stream>>>(Wa0, ba0, Wa1, ba1, Wo0, bo0, Wo1, bo1, (float*)ws);
  k_encode<<<(B_ * T_) / 64, 256, 0, stream>>>(action, obs, (const float*)ws,
                                               (f16*)(ws + WS_AENC), (f16*)(ws + WS_OENC));
  k_hprep<<<4096, 256, 0, stream>>>(Hf, Hm, Hl, (f16*)(ws + WS_H));
  hipMemsetAsync(ws + WS_FLAG, 0, 1024, stream);  // reset flags + lockstep counters
  k_main<<<256, 512, 0, stream>>>((const f16*)(ws + WS_AENC), (const f16*)(ws + WS_OENC),
                                  (const char*)(ws + WS_H), (float*)(ws + WS_U),
                                  (int*)(ws + WS_FLAG), (int*)(ws + WS_CNT), out);
}